// Round 1
// baseline (57.200 us; speedup 1.0000x reference)
//
#include <hip/hip_runtime.h>

// loss = sum_{b,m,n} | dot(src[b,n,:], tgts[b,m,n,:]) |
// B=64, M=16, N=64, D=1024 (read from in_sizes to stay generic)
//
// One wave (64 lanes) per (b,m,n) row: each lane reads 16 floats as 4x float4
// (coalesced 1KiB per wave per instruction), FMA into a scalar, 6-step
// shuffle reduce, |.|, per-block LDS combine, one atomicAdd per block.

__global__ __launch_bounds__(256) void orth_loss_kernel(
    const float* __restrict__ src,
    const float* __restrict__ tgts,
    float* __restrict__ out,
    int total_rows)   // B*M*N
{
    const int wave = threadIdx.x >> 6;   // 0..3
    const int lane = threadIdx.x & 63;

    float local = 0.0f;

    // grid-stride over rows; row order == tgts memory order (sequential HBM)
    for (int row = blockIdx.x * 4 + wave; row < total_rows;
         row += gridDim.x * 4) {
        const int n  = row & 63;         // N = 64
        const int bm = row >> 6;         // b*16 + m
        const int b  = bm >> 4;          // M = 16

        const float4* __restrict__ tp =
            reinterpret_cast<const float4*>(tgts + (size_t)row * 1024);
        const float4* __restrict__ sp =
            reinterpret_cast<const float4*>(src + ((size_t)(b * 64 + n)) * 1024);

        float dot = 0.0f;
#pragma unroll
        for (int k = 0; k < 4; ++k) {
            const float4 t = tp[lane + k * 64];
            const float4 s = sp[lane + k * 64];
            dot = fmaf(t.x, s.x, dot);
            dot = fmaf(t.y, s.y, dot);
            dot = fmaf(t.z, s.z, dot);
            dot = fmaf(t.w, s.w, dot);
        }

        // 64-lane butterfly reduce
#pragma unroll
        for (int off = 32; off > 0; off >>= 1)
            dot += __shfl_down(dot, off, 64);

        if (lane == 0) local += fabsf(dot);
    }

    __shared__ float sbuf[4];
    if (lane == 0) sbuf[wave] = local;
    __syncthreads();

    if (threadIdx.x == 0) {
        const float s = sbuf[0] + sbuf[1] + sbuf[2] + sbuf[3];
        atomicAdd(out, s);
    }
}

extern "C" void kernel_launch(void* const* d_in, const int* in_sizes, int n_in,
                              void* d_out, int out_size, void* d_ws, size_t ws_size,
                              hipStream_t stream) {
    const float* src  = (const float*)d_in[0];   // [B, N, D]
    const float* tgts = (const float*)d_in[1];   // [B, M, N, D]
    float* out = (float*)d_out;                  // [1]

    // B*M*N*D = in_sizes[1]; D = 1024 fixed by problem
    const int total_rows = in_sizes[1] / 1024;   // 65536

    hipMemsetAsync(out, 0, sizeof(float), stream);

    const int blocks = 2048;   // 256 CU x 8 blocks/CU; grid-stride covers rest
    orth_loss_kernel<<<blocks, 256, 0, stream>>>(src, tgts, out, total_rows);
}